// Round 3
// baseline (616.133 us; speedup 1.0000x reference)
//
#include <hip/hip_runtime.h>
#include <stdint.h>

// B=4,H=8,Lq=512,NB=32,NT=128,D=64. Outputs: out [B,Lq,H*D] then attn_w [B,H,Lq,NB,NT].
// Structure: 1 workgroup = 16 q-rows x one (b,h). 4 waves; each wave owns 8 FULL n-blocks
// (softmax is per-block -> fully in-wave, ZERO barriers in the main loop).
constexpr int CB=4, CH=8, CLQ=512, CNB=32, CNT=128, CD=64;
constexpr int QT=16;        // q rows per workgroup
constexpr int PSTR16=136;   // P LDS row stride in f16 units (=272B, 16B-aligned rows, conflict-free b128 reads)
constexpr int OSTR=68;      // O reduce row stride (f32); wave region 16*68*4 = 4352B == 16*136*2 (exact alias)

typedef __attribute__((ext_vector_type(8))) __fp16 half8;
typedef __attribute__((ext_vector_type(2))) __fp16 half2v;
typedef __attribute__((ext_vector_type(4))) float f32x4;

union HFrag { uint32_t u[4]; half8 h8; half2v h2[4]; };

__global__ __launch_bounds__(256, 4)
void sdpa_mfma_kernel(const float* __restrict__ qg, const float* __restrict__ kg,
                      const float* __restrict__ vg, const float* __restrict__ sg,
                      float* __restrict__ outg, float* __restrict__ awg)
{
    // per-wave P tile (16x128 f16); after the loop the SAME per-wave 4352B region is
    // reused (same-wave WAR, no barrier needed) as the f32 O-reduction buffer.
    __shared__ __align__(16) __fp16 pbuf[4 * QT * PSTR16];     // 17408 B
    __shared__ __align__(16) float as_t[CNB * QT];              // attn_s transposed [n][row], 2 KB

    const int tid  = threadIdx.x;
    const int wave = tid >> 6;
    const int lane = tid & 63;
    const int l15  = lane & 15;
    const int q8   = lane >> 4;

    // XCD-aware swizzle: 1024 wgs, 8 XCDs, 128 per XCD -> all 32 q-tiles of a (b,h)
    // run on one XCD so its 2MB K+V stays L2-hot.
    const int bid0 = blockIdx.x;
    const int bid  = (bid0 & 7) * 128 + (bid0 >> 3);
    const int qt  = bid & 31;
    const int bh  = bid >> 5;
    const int b   = bh >> 3;
    const int h   = bh & 7;
    const int q0  = qt * QT;

    // ---- stage attn_s transposed: as_t[n][r] ----
    {
        const float* sbase = sg + ((size_t)bh * CLQ + q0) * CNB;
        #pragma unroll
        for (int e = 0; e < 2; ++e) {
            int idx = tid + e * 256;          // 512 elems
            int r = idx >> 5, n = idx & 31;
            as_t[n * QT + r] = sbase[r * CNB + n];
        }
    }

    // ---- Q A-fragments (f16, persist): row = l15, k = s*32 + q8*8 + j ----
    HFrag qf[2];
    {
        const float* qrow = qg + ((size_t)bh * CLQ + q0 + l15) * CD;
        #pragma unroll
        for (int s = 0; s < 2; ++s) {
            f32x4 a = *(const f32x4*)&qrow[s*32 + q8*8];
            f32x4 c = *(const f32x4*)&qrow[s*32 + q8*8 + 4];
            qf[s].h2[0] = __builtin_amdgcn_cvt_pkrtz(a[0]*0.125f, a[1]*0.125f);
            qf[s].h2[1] = __builtin_amdgcn_cvt_pkrtz(a[2]*0.125f, a[3]*0.125f);
            qf[s].h2[2] = __builtin_amdgcn_cvt_pkrtz(c[0]*0.125f, c[1]*0.125f);
            qf[s].h2[3] = __builtin_amdgcn_cvt_pkrtz(c[2]*0.125f, c[3]*0.125f);
        }
    }

    f32x4 O[4];
    #pragma unroll
    for (int cd = 0; cd < 4; ++cd) O[cd] = (f32x4){0.f,0.f,0.f,0.f};

    __fp16* pw = &pbuf[wave * QT * PSTR16];

    __syncthreads();   // as_t ready — the ONLY barrier before the epilogue

    #pragma unroll 1
    for (int i = 0; i < 8; ++i) {
        const int n = (i << 2) | wave;      // each wave owns whole blocks
        const float* kb = kg + ((size_t)((b*CNB + n)*CH + h)) * CNT * CD;
        const float* vb = vg + ((size_t)((b*CNB + n)*CH + h)) * CNT * CD;

        // ---- QK^T over all 128 tokens: 8 c-tiles, single f16 product (K=64 -> 2 MFMA each) ----
        float Ev[8][4];                      // exp(S): [c][r], token = c*16+l15, row = q8*4+r
        #pragma unroll
        for (int c = 0; c < 8; ++c) {
            const float* kr = kb + (size_t)(c*16 + l15) * CD;
            HFrag kf[2];
            #pragma unroll
            for (int s = 0; s < 2; ++s) {
                f32x4 a = *(const f32x4*)&kr[s*32 + q8*8];
                f32x4 d = *(const f32x4*)&kr[s*32 + q8*8 + 4];
                kf[s].h2[0] = __builtin_amdgcn_cvt_pkrtz(a[0], a[1]);
                kf[s].h2[1] = __builtin_amdgcn_cvt_pkrtz(a[2], a[3]);
                kf[s].h2[2] = __builtin_amdgcn_cvt_pkrtz(d[0], d[1]);
                kf[s].h2[3] = __builtin_amdgcn_cvt_pkrtz(d[2], d[3]);
            }
            f32x4 acc = (f32x4){0.f,0.f,0.f,0.f};
            acc = __builtin_amdgcn_mfma_f32_16x16x32_f16(qf[0].h8, kf[0].h8, acc, 0, 0, 0);
            acc = __builtin_amdgcn_mfma_f32_16x16x32_f16(qf[1].h8, kf[1].h8, acc, 0, 0, 0);
            // no max-subtraction: |S| <~ 7, exp safe in fp32 (same as verified baseline)
            #pragma unroll
            for (int r = 0; r < 4; ++r) Ev[c][r] = __expf(acc[r]);
        }

        // ---- per-row softmax denominator, fully in-wave ----
        float ps[4];
        #pragma unroll
        for (int r = 0; r < 4; ++r)
            ps[r] = ((Ev[0][r]+Ev[1][r]) + (Ev[2][r]+Ev[3][r]))
                  + ((Ev[4][r]+Ev[5][r]) + (Ev[6][r]+Ev[7][r]));
        #pragma unroll
        for (int off = 1; off <= 8; off <<= 1) {
            #pragma unroll
            for (int r = 0; r < 4; ++r) ps[r] += __shfl_xor(ps[r], off, 64);
        }

        const f32x4 asv = *(const f32x4*)&as_t[n*QT + q8*4];
        float fac[4];
        #pragma unroll
        for (int r = 0; r < 4; ++r) fac[r] = asv[r] * __builtin_amdgcn_rcpf(ps[r]);

        // ---- attn_w directly from registers (exact f32) + P -> LDS as f16 ----
        float* aw0 = awg + (((size_t)bh*CLQ + q0 + q8*4)*CNB + n)*CNT + l15;
        __fp16* pwb = pw + (q8*4)*PSTR16 + l15;
        #pragma unroll
        for (int r = 0; r < 4; ++r) {
            #pragma unroll
            for (int c = 0; c < 8; ++c) {
                float wv = Ev[c][r] * fac[r];
                aw0[(size_t)r*(CNB*CNT) + c*16] = wv;
                pwb[r*PSTR16 + c*16] = (__fp16)wv;   // RTE cvt + ds_write_b16, imm offsets
            }
        }

        // ---- PV: A = P (from LDS, direct f16 frag), B = V (scalar loads + pkrtz) ----
        #pragma unroll
        for (int ks = 0; ks < 4; ++ks) {
            HFrag pa;
            pa.h8 = *(const half8*)&pw[l15*PSTR16 + ks*32 + q8*8];   // row=l15, k=ks*32+q8*8+j
            const float* vrow = vb + (size_t)(ks*32 + q8*8)*CD + l15;
            #pragma unroll
            for (int cd = 0; cd < 4; ++cd) {
                HFrag vf;
                #pragma unroll
                for (int p = 0; p < 4; ++p) {
                    float v0 = vrow[(2*p)*CD + cd*16];
                    float v1 = vrow[(2*p+1)*CD + cd*16];
                    vf.h2[p] = __builtin_amdgcn_cvt_pkrtz(v0, v1);
                }
                O[cd] = __builtin_amdgcn_mfma_f32_16x16x32_f16(pa.h8, vf.h8, O[cd], 0, 0, 0);
            }
        }
    }

    // ---- cross-wave O reduction (pbuf region reused as f32 buffer; per-wave regions alias exactly) ----
    float* obase = (float*)pbuf;
    {
        float* ow = obase + wave * QT * OSTR;
        #pragma unroll
        for (int cd = 0; cd < 4; ++cd)
            #pragma unroll
            for (int r = 0; r < 4; ++r)
                ow[(q8*4 + r)*OSTR + cd*16 + l15] = O[cd][r];
    }
    __syncthreads();
    {
        int r = tid >> 4, dq = tid & 15;
        f32x4 acc = (f32x4){0.f,0.f,0.f,0.f};
        #pragma unroll
        for (int wv = 0; wv < 4; ++wv)
            acc += *(const f32x4*)&obase[wv*QT*OSTR + r*OSTR + dq*4];
        *(f32x4*)&outg[((size_t)b*CLQ + q0 + r)*(CH*CD) + h*CD + dq*4] = acc;
    }
}

extern "C" void kernel_launch(void* const* d_in, const int* in_sizes, int n_in,
                              void* d_out, int out_size, void* d_ws, size_t ws_size,
                              hipStream_t stream) {
    const float* q = (const float*)d_in[0];
    const float* k = (const float*)d_in[1];
    const float* v = (const float*)d_in[2];
    const float* s = (const float*)d_in[3];
    float* out = (float*)d_out;
    float* aw  = out + (size_t)CB * CLQ * CH * CD;

    const int grid = CB * CH * (CLQ / QT);   // 1024
    sdpa_mfma_kernel<<<grid, 256, 0, stream>>>(q, k, v, s, out, aw);
}